// Round 7
// baseline (207.035 us; speedup 1.0000x reference)
//
#include <hip/hip_runtime.h>
#include <hip/hip_bf16.h>

namespace {

constexpr int B = 4;
constexpr int N = 8192;     // 2^13
constexpr int D = 16;
constexpr int R = 32;
constexpr int H = 64;
constexpr int E = 262144;   // 2^18

typedef __attribute__((ext_vector_type(8))) short short8;   // 8 x bf16 (4 VGPRs)
typedef __attribute__((ext_vector_type(4))) short short4v;  // 4 x bf16 (2 VGPRs)
typedef __attribute__((ext_vector_type(4))) float f32x4;    // MFMA accumulator

__device__ __forceinline__ float4 ld4(const float* p) {
    return *reinterpret_cast<const float4*>(p);
}
__device__ __forceinline__ float4 fma4(float a, float4 w, float4 c) {
    return float4{fmaf(a, w.x, c.x), fmaf(a, w.y, c.y),
                  fmaf(a, w.z, c.z), fmaf(a, w.w, c.w)};
}
__device__ __forceinline__ float4 relu4(float4 v) {
    return float4{fmaxf(v.x, 0.f), fmaxf(v.y, 0.f), fmaxf(v.z, 0.f), fmaxf(v.w, 0.f)};
}
__device__ __forceinline__ short bf16s(float f) {
    __hip_bfloat16 h = __float2bfloat16(f);   // RNE
    return __builtin_bit_cast(short, h);
}
__device__ __forceinline__ short8 pack8(float4 a, float4 b) {
    short8 o;
    o[0] = bf16s(a.x); o[1] = bf16s(a.y); o[2] = bf16s(a.z); o[3] = bf16s(a.w);
    o[4] = bf16s(b.x); o[5] = bf16s(b.y); o[6] = bf16s(b.z); o[7] = bf16s(b.w);
    return o;
}
// relu + pack 4 accumulator floats into 4 bf16
__device__ __forceinline__ short4v pack4_relu(f32x4 c) {
    short4v o;
    o[0] = bf16s(fmaxf(c[0], 0.f)); o[1] = bf16s(fmaxf(c[1], 0.f));
    o[2] = bf16s(fmaxf(c[2], 0.f)); o[3] = bf16s(fmaxf(c[3], 0.f));
    return o;
}
// concat two packed short4v into an MFMA A/B fragment (pure register op)
__device__ __forceinline__ short8 cat44(short4v a, short4v b) {
    int2 ia = __builtin_bit_cast(int2, a);
    int2 ib = __builtin_bit_cast(int2, b);
    int4 v{ia.x, ia.y, ib.x, ib.y};
    return __builtin_bit_cast(short8, v);
}
// extract position i (0..31) from 4x int4 of packed bf16 (i must be compile-time)
__device__ __forceinline__ float red_get(const int4* uu, int i) {
    const int wsel = i >> 1;
    const int4 v = uu[wsel >> 2];
    const int word = (wsel & 3) == 0 ? v.x : (wsel & 3) == 1 ? v.y
                   : (wsel & 3) == 2 ? v.z : v.w;
    return (i & 1) ? __builtin_bit_cast(float, word & 0xffff0000)
                   : __builtin_bit_cast(float, (unsigned)word << 16);
}

constexpr int RED_S = 264;   // red stride in shorts; %8==0 keeps b128 reads 16B-aligned

// hidden-permutation for layer-2/4 row packing (R5-verified): the C/D accumulator
// of layer 1/3 (lane q*16+l15, tile mt, reg rg = hidden mt*16+q*4+rg) is consumed
// DIRECTLY as the next layer's A/B fragment (k = q*8+j) iff row k sources hidden
//   rho(k) = 32*(k>>5) + ((k>>2)&1)*16 + ((k>>3)&3)*4 + (k&3)
// Then h0 = concat(tile0,tile1), h1 = concat(tile2,tile3): NO LDS transpose.

__device__ __forceinline__ void prepack_w12(
    int t, const float* __restrict__ W1, const float* __restrict__ W2,
    short* __restrict__ w1p, short* __restrict__ w2p)
{
    // A/B-frag mapping (mfma_f32_16x16x32_bf16, verified m89):
    //   m|n = lane&15, k = (lane>>4)*8 + j  (identical for A and B)
    for (int i = t; i < 4 * 64 * 8; i += 256) {
        int j = i & 7, lane = (i >> 3) & 63, ct = i >> 9;
        int k = (lane >> 4) * 8 + j, n = ct * 16 + (lane & 15);
        w1p[i] = bf16s(W1[k * H + n]);
    }
    for (int i = t; i < 4 * 64 * 8; i += 256) {
        int j = i & 7, lane = (i >> 3) & 63, idx = i >> 9;
        int ct = idx >> 1, kc = idx & 1;
        // rho-remapped row: was kc*32 + (lane>>4)*8 + j
        int k = kc * 32 + (j >> 2) * 16 + ((lane >> 4) & 3) * 4 + (j & 3);
        int f = ct * 16 + (lane & 15);
        w2p[i] = bf16s(W2[k * R + f]);
    }
}
__device__ __forceinline__ void prepack_w34(
    int t, const float* __restrict__ W3, const float* __restrict__ W4,
    short* __restrict__ w3p, short* __restrict__ w4p)
{
    for (int i = t; i < 8 * 64 * 8; i += 256) {
        int j = i & 7, lane = (i >> 3) & 63, idx = i >> 9;
        int ct = idx >> 1, kc = idx & 1;
        int k = kc * 32 + (lane >> 4) * 8 + j, n = ct * 16 + (lane & 15);
        w3p[i] = (k < D + R) ? bf16s(W3[k * H + n]) : (short)0;
    }
    for (int i = t; i < 2 * 64 * 8; i += 256) {
        int j = i & 7, lane = (i >> 3) & 63, kc = i >> 9;
        // rho-remapped row: was kc*32 + (lane>>4)*8 + j
        int k = kc * 32 + (j >> 2) * 16 + ((lane >> 4) & 3) * 4 + (j & 3);
        int d = lane & 15;
        w4p[i] = bf16s(W4[k * D + d]);
    }
}

// ---------------------------------------------------------------------------
// Dispatch 2 (megasort): hist + scan + scatter fused via release/acquire
// flags, plus weight prepack and rel zeroing.
//   blocks 0..1023 : histogram -> RELEASE done++ -> spin sflag -> scatter
//   block  0 extra : spin done==1024 -> fence -> scan (plain int4 loads,
//                    the R6-proven fast path) -> fence -> RELEASE sflag
//   block  1024    : weight prepack
//   blocks 1025+   : rel zeroing
// Deadlock-free: __launch_bounds__(256,5) -> >=5 blocks/CU -> 1280 resident
// slots >= the 1024-block spin group; independent blocks always retire.
// done/sflag are in the memset-zeroed region (workspace poison-proof).
// ---------------------------------------------------------------------------
__global__ __launch_bounds__(256, 5) void megasort_kernel(
    const int* __restrict__ senders, const int* __restrict__ receivers,
    int* __restrict__ cnt, int* __restrict__ done, int* __restrict__ sflag,
    int* __restrict__ pos, int2* __restrict__ sr,
    const float* __restrict__ W1, const float* __restrict__ W2,
    const float* __restrict__ W3, const float* __restrict__ W4,
    short* __restrict__ w1p, short* __restrict__ w2p,
    short* __restrict__ w3p, short* __restrict__ w4p,
    float4* __restrict__ relz)
{
    const int tid = threadIdx.x;
    const int bid = blockIdx.x;

    if (bid >= 1024) {
        if (bid == 1024) {
            prepack_w12(tid, W1, W2, w1p, w2p);
            prepack_w34(tid, W3, W4, w3p, w4p);
        } else {
            const int base = (bid - 1025) * 256 + tid;
            #pragma unroll
            for (int i = 0; i < 8; ++i)
                relz[base + i * 32768] = float4{0.f, 0.f, 0.f, 0.f};
        }
        return;
    }

    // ---- histogram ----
    const int e = bid * 256 + tid;
    const int r = receivers[e];
    const int s = senders[e];          // kept in reg for the scatter stage
    atomicAdd(cnt + r, 1);
    __syncthreads();                   // vmcnt(0): this block's cnt atomics acked
    if (tid == 0)
        __hip_atomic_fetch_add(done, 1, __ATOMIC_RELEASE,
                               __HIP_MEMORY_SCOPE_AGENT);

    if (bid == 0) {
        // ---- wait for all histogram blocks ----
        if (tid == 0) {
            while (__hip_atomic_load(done, __ATOMIC_RELAXED,
                                     __HIP_MEMORY_SCOPE_AGENT) < 1024)
                __builtin_amdgcn_s_sleep(8);
        }
        __syncthreads();
        __threadfence();               // acquire side: invalidate stale cache

        // ---- scan: 8192 counts, 32/thread, plain vectorized loads ----
        int4 c4[8];
        const int4* cp = reinterpret_cast<const int4*>(cnt) + tid * 8;
        #pragma unroll
        for (int i = 0; i < 8; ++i) c4[i] = cp[i];
        int s0 = 0;
        #pragma unroll
        for (int i = 0; i < 8; ++i) s0 += c4[i].x + c4[i].y + c4[i].z + c4[i].w;
        const int lane = tid & 63, wv = tid >> 6;
        int incl = s0;
        #pragma unroll
        for (int d2 = 1; d2 < 64; d2 <<= 1) {
            int v = __shfl_up(incl, d2, 64);
            if (lane >= d2) incl += v;
        }
        __shared__ int wtot[4];
        if (lane == 63) wtot[wv] = incl;
        __syncthreads();
        int base = incl - s0;
        #pragma unroll
        for (int i = 0; i < 4; ++i) base += (i < wv) ? wtot[i] : 0;
        int4* po = reinterpret_cast<int4*>(pos) + tid * 8;
        #pragma unroll
        for (int i = 0; i < 8; ++i) {
            int4 cv = c4[i], o;
            o.x = base; base += cv.x;
            o.y = base; base += cv.y;
            o.z = base; base += cv.z;
            o.w = base; base += cv.w;
            po[i] = o;
        }
        __syncthreads();               // drain pos stores (vmcnt 0)
        __threadfence();               // wbl2: flush pos to coherence point
        if (tid == 0)
            __hip_atomic_store(sflag, 1, __ATOMIC_RELEASE,
                               __HIP_MEMORY_SCOPE_AGENT);
        // fall through to scatter (pos flushed; own stores visible to atomics)
    } else {
        if (tid == 0) {
            while (__hip_atomic_load(sflag, __ATOMIC_RELAXED,
                                     __HIP_MEMORY_SCOPE_AGENT) == 0)
                __builtin_amdgcn_s_sleep(8);
        }
        __syncthreads();               // whole block waits on tid0's spin
    }

    // ---- scatter (blocks still resident; s,r already in registers) ----
    const int p = atomicAdd(pos + r, 1);
    sr[p] = int2{s, r};
}

// ---------------------------------------------------------------------------
// Dispatch 3: MFMA edge MLP + two-stage segmented reduction (4096 blocks).
// rho-remap: no LDS transpose (R5-verified). Two-stage reduction (R4-verified):
// only first/last receivers of a window can straddle blocks -> atomicAdd;
// interior receivers -> plain stores into pre-zeroed rel.
// ---------------------------------------------------------------------------
__global__ __launch_bounds__(256, 4) void edge_mfma_kernel(
    const float* __restrict__ particles,
    const int2*  __restrict__ sr,
    const short* __restrict__ w1p, const float* __restrict__ b1,
    const short* __restrict__ w2p, const float* __restrict__ b2,
    float* __restrict__ rel)
{
    __shared__ short red[R * RED_S];          // [f][pos] bf16, stride 264 (16.9 KB)
    __shared__ int   rs[256];
    __shared__ float pre[8][33];              // first-segment sum per (group,feat)
    __shared__ float suf[8][33];              // last-segment sum per (group,feat)
    __shared__ int   kcnt[8];                 // segments per group

    const int tid  = threadIdx.x;
    const int lane = tid & 63;
    const int w    = tid >> 6;
    const int b    = blockIdx.x >> 10;        // 1024 blocks per batch
    const int p0   = (blockIdx.x & 1023) * 256;
    const int l15  = lane & 15;
    const int q    = lane >> 4;

    const int2 srv = sr[p0 + tid];
    rs[tid] = srv.y;

    // hoisted gather: distribute rows via shfl, issue all 8 dwordx4 loads up front
    float4 a0[4], a1[4];
    #pragma unroll
    for (int t = 0; t < 4; ++t) {
        int srow = __shfl(srv.x, t * 16 + l15);
        int rrow = __shfl(srv.y, t * 16 + l15);
        int row = (q < 2) ? srow : rrow;
        const float* src = particles + ((size_t)b * N + row) * D + (q & 1) * 8;
        a0[t] = ld4(src);
        a1[t] = ld4(src + 4);
    }

    // weight fragments (L2-hot, coalesced)
    short8 w1f[4], w2f[4];
    #pragma unroll
    for (int mt = 0; mt < 4; ++mt)
        w1f[mt] = *reinterpret_cast<const short8*>(w1p + (mt * 64 + lane) * 8);
    #pragma unroll
    for (int i = 0; i < 4; ++i)
        w2f[i] = *reinterpret_cast<const short8*>(w2p + (i * 64 + lane) * 8);

    f32x4 bias1[4];
    #pragma unroll
    for (int mt = 0; mt < 4; ++mt) {
        float4 t4 = ld4(b1 + mt * 16 + q * 4);
        bias1[mt] = f32x4{t4.x, t4.y, t4.z, t4.w};
    }
    const float bias2a = b2[l15];
    const float bias2b = b2[16 + l15];

    short8 af[4];
    #pragma unroll
    for (int t = 0; t < 4; ++t) af[t] = pack8(a0[t], a1[t]);

    #pragma unroll
    for (int t = 0; t < 4; ++t) {
        // layer1: 4 hidden m-tiles, K=32 -> packed bf16 kept in registers
        f32x4 c0 = __builtin_amdgcn_mfma_f32_16x16x32_bf16(w1f[0], af[t], bias1[0], 0, 0, 0);
        f32x4 c1 = __builtin_amdgcn_mfma_f32_16x16x32_bf16(w1f[1], af[t], bias1[1], 0, 0, 0);
        f32x4 c2 = __builtin_amdgcn_mfma_f32_16x16x32_bf16(w1f[2], af[t], bias1[2], 0, 0, 0);
        f32x4 c3 = __builtin_amdgcn_mfma_f32_16x16x32_bf16(w1f[3], af[t], bias1[3], 0, 0, 0);
        short8 h0 = cat44(pack4_relu(c0), pack4_relu(c1));   // k = 0..31 (rho rows)
        short8 h1 = cat44(pack4_relu(c2), pack4_relu(c3));   // k = 32..63

        // layer2: D2[edge][f], 2 f-tiles, K=64
        f32x4 r0 = {bias2a, bias2a, bias2a, bias2a};
        f32x4 r1 = {bias2b, bias2b, bias2b, bias2b};
        r0 = __builtin_amdgcn_mfma_f32_16x16x32_bf16(h0, w2f[0], r0, 0, 0, 0);
        r0 = __builtin_amdgcn_mfma_f32_16x16x32_bf16(h1, w2f[1], r0, 0, 0, 0);
        r1 = __builtin_amdgcn_mfma_f32_16x16x32_bf16(h0, w2f[2], r1, 0, 0, 0);
        r1 = __builtin_amdgcn_mfma_f32_16x16x32_bf16(h1, w2f[3], r1, 0, 0, 0);

        const int pb2 = w * 64 + t * 16 + q * 4;
        *reinterpret_cast<short4v*>(red + l15 * RED_S + pb2)        = pack4_relu(r0);
        *reinterpret_cast<short4v*>(red + (16 + l15) * RED_S + pb2) = pack4_relu(r1);
    }
    __syncthreads();

    // ---- stage 1: per-(group,feature) segmented partial sums ----
    const int g2 = tid >> 5;
    const int f  = tid & 31;
    const int gb = g2 * 32;
    float* relb = rel + (size_t)b * N * R;

    unsigned bmask = 0;
    int first;
    {
        int4 r4[8];
        #pragma unroll
        for (int i = 0; i < 8; ++i)
            r4[i] = *reinterpret_cast<const int4*>(rs + gb + 4 * i);
        first = r4[0].x;
        int prev = first;
        #pragma unroll
        for (int i = 1; i < 32; ++i) {
            const int4 v4 = r4[i >> 2];
            const int rr = (i & 3) == 0 ? v4.x : (i & 3) == 1 ? v4.y
                         : (i & 3) == 2 ? v4.z : v4.w;
            if (rr != prev) bmask |= (1u << i);
            prev = rr;
        }
    }
    if (f == 0) kcnt[g2] = __popc(bmask) + 1;

    int4 uu[4];
    #pragma unroll
    for (int i = 0; i < 4; ++i)
        uu[i] = *reinterpret_cast<const int4*>(red + f * RED_S + gb + 8 * i);

    {
        float acc = 0.f;
        int cur = first;
        int seg = 0;
        #pragma unroll
        for (int i = 0; i < 32; ++i) {
            if (bmask & (1u << i)) {
                if (seg == 0) pre[g2][f] = acc;
                else relb[(size_t)cur * R + f] = acc;   // interior complete receiver
                ++seg;
                acc = 0.f;
                cur = rs[gb + i];
            }
            acc += red_get(uu, i);
        }
        suf[g2][f] = acc;   // last segment (k==1: whole group; pre unwritten)
    }
    __syncthreads();

    // ---- stage 2: merge chains across groups (one thread per feature) ----
    if (tid < 32) {
        int   cur2 = rs[0];
        float a2   = 0.f;
        int   nfl  = 0;
        #pragma unroll
        for (int g = 0; g < 8; ++g) {
            const int   rf   = rs[g * 32];
            const int   rl   = rs[g * 32 + 31];
            const int   kk   = kcnt[g];
            const float sufv = suf[g][tid];
            if (kk == 1) {
                if (rf == cur2) a2 += sufv;
                else {
                    if (nfl == 0) atomicAdd(relb + (size_t)cur2 * R + tid, a2);
                    else          relb[(size_t)cur2 * R + tid] = a2;
                    ++nfl;
                    cur2 = rf; a2 = sufv;
                }
            } else {
                const float prev = pre[g][tid];
                if (rf == cur2) {
                    a2 += prev;
                    if (nfl == 0) atomicAdd(relb + (size_t)cur2 * R + tid, a2);
                    else          relb[(size_t)cur2 * R + tid] = a2;
                    ++nfl;
                } else {
                    if (nfl == 0) atomicAdd(relb + (size_t)cur2 * R + tid, a2);
                    else          relb[(size_t)cur2 * R + tid] = a2;
                    ++nfl;
                    relb[(size_t)rf * R + tid] = prev;   // complete receiver
                    ++nfl;
                }
                cur2 = rl; a2 = sufv;
            }
        }
        atomicAdd(relb + (size_t)cur2 * R + tid, a2);   // may span into next window
    }
}

// ---------------------------------------------------------------------------
// Dispatch 4: MFMA node MLP, one 16-node tile per wave. Zero LDS (rho-remap).
// ---------------------------------------------------------------------------
__global__ __launch_bounds__(256, 4) void node_mfma_kernel(
    const float* __restrict__ particles,
    const float* __restrict__ rel,
    const short* __restrict__ w3p, const float* __restrict__ b3,
    const short* __restrict__ w4p, const float* __restrict__ b4,
    float* __restrict__ out)
{
    const int tid  = threadIdx.x;
    const int lane = tid & 63;
    const int w    = tid >> 6;
    const int tile = blockIdx.x * 4 + w;        // [0, B*N/16)
    const int b    = tile >> 9;                 // 512 tiles per batch
    const int l15  = lane & 15;
    const int q    = lane >> 4;
    const int node = (tile & 511) * 16 + l15;

    const float* prow = particles + ((size_t)b * N + node) * D;
    const float* rrow = rel + ((size_t)b * N + node) * R;

    const float* src0 = (q < 2) ? (prow + (q & 1) * 8) : (rrow + (q & 1) * 8);
    float4 c0a = ld4(src0), c0b = ld4(src0 + 4);
    float4 c1a = {0.f, 0.f, 0.f, 0.f}, c1b = {0.f, 0.f, 0.f, 0.f};
    if (q < 2) { c1a = ld4(rrow + 16 + q * 8); c1b = ld4(rrow + 20 + q * 8); }

    short8 w3f[8], w4f[2];
    #pragma unroll
    for (int i = 0; i < 8; ++i)
        w3f[i] = *reinterpret_cast<const short8*>(w3p + (i * 64 + lane) * 8);
    #pragma unroll
    for (int i = 0; i < 2; ++i)
        w4f[i] = *reinterpret_cast<const short8*>(w4p + (i * 64 + lane) * 8);

    f32x4 bias3[4];
    #pragma unroll
    for (int mt = 0; mt < 4; ++mt) {
        float4 t4 = ld4(b3 + mt * 16 + q * 4);
        bias3[mt] = f32x4{t4.x, t4.y, t4.z, t4.w};
    }
    f32x4 bias4;
    { float4 t4 = ld4(b4 + q * 4); bias4 = f32x4{t4.x, t4.y, t4.z, t4.w}; }

    short8 a0 = pack8(c0a, c0b);
    short8 a1 = pack8(c1a, c1b);

    // layer3: 4 hidden m-tiles, K=48 (padded 64) -> packed in registers
    f32x4 c0 = bias3[0], c1 = bias3[1], c2 = bias3[2], c3 = bias3[3];
    c0 = __builtin_amdgcn_mfma_f32_16x16x32_bf16(w3f[0], a0, c0, 0, 0, 0);
    c0 = __builtin_amdgcn_mfma_f32_16x16x32_bf16(w3f[1], a1, c0, 0, 0, 0);
    c1 = __builtin_amdgcn_mfma_f32_16x16x32_bf16(w3f[2], a0, c1, 0, 0, 0);
    c1 = __builtin_amdgcn_mfma_f32_16x16x32_bf16(w3f[3], a1, c1, 0, 0, 0);
    c2 = __builtin_amdgcn_mfma_f32_16x16x32_bf16(w3f[4], a0, c2, 0, 0, 0);
    c2 = __builtin_amdgcn_mfma_f32_16x16x32_bf16(w3f[5], a1, c2, 0, 0, 0);
    c3 = __builtin_amdgcn_mfma_f32_16x16x32_bf16(w3f[6], a0, c3, 0, 0, 0);
    c3 = __builtin_amdgcn_mfma_f32_16x16x32_bf16(w3f[7], a1, c3, 0, 0, 0);
    short8 h0 = cat44(pack4_relu(c0), pack4_relu(c1));   // k = 0..31 (rho rows)
    short8 h1 = cat44(pack4_relu(c2), pack4_relu(c3));   // k = 32..63

    f32x4 r = bias4;
    r = __builtin_amdgcn_mfma_f32_16x16x32_bf16(w4f[0], h0, r, 0, 0, 0);
    r = __builtin_amdgcn_mfma_f32_16x16x32_bf16(w4f[1], h1, r, 0, 0, 0);

    float4 pv = ld4(prow + q * 4);
    float4* po = reinterpret_cast<float4*>(out + ((size_t)b * N + node) * D + q * 4);
    *po = float4{pv.x + r[0], pv.y + r[1], pv.z + r[2], pv.w + r[3]};
}

// ---------- fallback path (fp32, correctness backstop) ----------

__global__ __launch_bounds__(256, 2) void edge_atomic_kernel(
    const float* __restrict__ particles,
    const int*   __restrict__ senders,
    const int*   __restrict__ receivers,
    const float* __restrict__ W1, const float* __restrict__ b1,
    const float* __restrict__ W2, const float* __restrict__ b2,
    float* __restrict__ rel)
{
    const int idx = blockIdx.x * 256 + threadIdx.x;
    const int b = idx >> 18;
    const int e = idx & (E - 1);
    const int s = senders[e];
    const int r = receivers[e];

    float4 ein4[8];
    {
        const float4* ps = reinterpret_cast<const float4*>(particles + ((size_t)b * N + s) * D);
        const float4* pr = reinterpret_cast<const float4*>(particles + ((size_t)b * N + r) * D);
        #pragma unroll
        for (int qq = 0; qq < 4; ++qq) ein4[qq] = ps[qq];
        #pragma unroll
        for (int qq = 0; qq < 4; ++qq) ein4[4 + qq] = pr[qq];
    }
    float4 rf4[8];
    #pragma unroll
    for (int qq = 0; qq < 8; ++qq) rf4[qq] = ld4(b2 + 4 * qq);

    for (int j4 = 0; j4 < H / 4; ++j4) {
        float4 h = ld4(b1 + 4 * j4);
        const float* w1c = W1 + 4 * j4;
        #pragma unroll
        for (int kv = 0; kv < 8; ++kv) {
            const float4 ev = ein4[kv];
            h = fma4(ev.x, ld4(w1c + (4 * kv + 0) * H), h);
            h = fma4(ev.y, ld4(w1c + (4 * kv + 1) * H), h);
            h = fma4(ev.z, ld4(w1c + (4 * kv + 2) * H), h);
            h = fma4(ev.w, ld4(w1c + (4 * kv + 3) * H), h);
        }
        h = relu4(h);
        const float* w2r = W2 + (4 * j4) * R;
        #pragma unroll
        for (int qq = 0; qq < 4; ++qq) {
            const float hq = (qq == 0) ? h.x : (qq == 1) ? h.y : (qq == 2) ? h.z : h.w;
            #pragma unroll
            for (int r4 = 0; r4 < 8; ++r4)
                rf4[r4] = fma4(hq, ld4(w2r + qq * R + 4 * r4), rf4[r4]);
        }
    }
    float* dst = rel + ((size_t)b * N + r) * R;
    #pragma unroll
    for (int r4 = 0; r4 < 8; ++r4) {
        float4 v = relu4(rf4[r4]);
        atomicAdd(dst + 4 * r4 + 0, v.x);
        atomicAdd(dst + 4 * r4 + 1, v.y);
        atomicAdd(dst + 4 * r4 + 2, v.z);
        atomicAdd(dst + 4 * r4 + 3, v.w);
    }
}

__global__ __launch_bounds__(256, 2) void node_valu_kernel(
    const float* __restrict__ particles,
    const float* __restrict__ rel,
    const float* __restrict__ W3, const float* __restrict__ b3,
    const float* __restrict__ W4, const float* __restrict__ b4,
    float* __restrict__ out)
{
    const int idx = blockIdx.x * 256 + threadIdx.x;
    float4 in4[12];
    {
        const float4* pp = reinterpret_cast<const float4*>(particles + (size_t)idx * D);
        #pragma unroll
        for (int qq = 0; qq < 4; ++qq) in4[qq] = pp[qq];
        const float4* pr = reinterpret_cast<const float4*>(rel + (size_t)idx * R);
        #pragma unroll
        for (int qq = 0; qq < 8; ++qq) in4[4 + qq] = pr[qq];
    }
    float4 dl4[4];
    #pragma unroll
    for (int qq = 0; qq < 4; ++qq) dl4[qq] = ld4(b4 + 4 * qq);

    for (int j4 = 0; j4 < H / 4; ++j4) {
        float4 h = ld4(b3 + 4 * j4);
        const float* w3c = W3 + 4 * j4;
        #pragma unroll
        for (int kv = 0; kv < 12; ++kv) {
            const float4 ev = in4[kv];
            h = fma4(ev.x, ld4(w3c + (4 * kv + 0) * H), h);
            h = fma4(ev.y, ld4(w3c + (4 * kv + 1) * H), h);
            h = fma4(ev.z, ld4(w3c + (4 * kv + 2) * H), h);
            h = fma4(ev.w, ld4(w3c + (4 * kv + 3) * H), h);
        }
        h = relu4(h);
        const float* w4r = W4 + (4 * j4) * D;
        #pragma unroll
        for (int qq = 0; qq < 4; ++qq) {
            const float hq = (qq == 0) ? h.x : (qq == 1) ? h.y : (qq == 2) ? h.z : h.w;
            #pragma unroll
            for (int d4 = 0; d4 < 4; ++d4)
                dl4[d4] = fma4(hq, ld4(w4r + qq * D + 4 * d4), dl4[d4]);
        }
    }
    float4* po = reinterpret_cast<float4*>(out + (size_t)idx * D);
    #pragma unroll
    for (int qq = 0; qq < 4; ++qq) {
        float4 v = dl4[qq];
        float4 pv = in4[qq];
        po[qq] = float4{pv.x + v.x, pv.y + v.y, pv.z + v.z, pv.w + v.w};
    }
}

}  // namespace

extern "C" void kernel_launch(void* const* d_in, const int* in_sizes, int n_in,
                              void* d_out, int out_size, void* d_ws, size_t ws_size,
                              hipStream_t stream) {
    const float* particles = (const float*)d_in[0];
    const int*   senders   = (const int*)d_in[1];
    const int*   receivers = (const int*)d_in[2];
    const float* W1 = (const float*)d_in[3];
    const float* b1 = (const float*)d_in[4];
    const float* W2 = (const float*)d_in[5];
    const float* b2 = (const float*)d_in[6];
    const float* W3 = (const float*)d_in[7];
    const float* b3 = (const float*)d_in[8];
    const float* W4 = (const float*)d_in[9];
    const float* b4 = (const float*)d_in[10];
    float* out = (float*)d_out;

    // workspace layout (256-B aligned slices)
    char* ws = (char*)d_ws;
    size_t off = 0;
    auto take = [&](size_t bytes) -> char* {
        char* p = ws + off;
        off = (off + bytes + 255) & ~(size_t)255;
        return p;
    };
    int*   cnt     = (int*)  take((size_t)N * 4 + 8);  // cnt[N], done, sflag
    int*   done    = cnt + N;
    int*   sflag   = cnt + N + 1;
    int*   pos     = (int*)  take((size_t)N * 4);
    int2*  sr      = (int2*) take((size_t)E * 8);
    float* rel     = (float*)take((size_t)B * N * R * 4);
    short* w1p     = (short*)take((size_t)4 * 64 * 8 * 2);
    short* w2p     = (short*)take((size_t)4 * 64 * 8 * 2);
    short* w3p     = (short*)take((size_t)8 * 64 * 8 * 2);
    short* w4p     = (short*)take((size_t)2 * 64 * 8 * 2);
    const bool fast = (off <= ws_size);

    if (fast) {
        // one memset covers cnt + done + sflag (flags must be poison-proof)
        hipMemsetAsync(cnt, 0, (size_t)N * 4 + 8, stream);
        megasort_kernel<<<1153, 256, 0, stream>>>(
            senders, receivers, cnt, done, sflag, pos, sr,
            W1, W2, W3, W4, w1p, w2p, w3p, w4p, (float4*)rel);
        edge_mfma_kernel<<<(B * E) / 256, 256, 0, stream>>>(
            particles, sr, w1p, b1, w2p, b2, rel);
        node_mfma_kernel<<<(B * N / 16) / 4, 256, 0, stream>>>(
            particles, rel, w3p, b3, w4p, b4, out);
    } else {
        float* rel0 = (float*)d_ws;
        hipMemsetAsync(rel0, 0, (size_t)B * N * R * 4, stream);
        edge_atomic_kernel<<<(B * E) / 256, 256, 0, stream>>>(
            particles, senders, receivers, W1, b1, W2, b2, rel0);
        node_valu_kernel<<<(B * N) / 256, 256, 0, stream>>>(
            particles, rel0, W3, b3, W4, b4, out);
    }
}

// Round 8
// 136.330 us; speedup vs baseline: 1.5186x; 1.5186x over previous
//
#include <hip/hip_runtime.h>
#include <hip/hip_bf16.h>

namespace {

constexpr int B = 4;
constexpr int N = 8192;     // 2^13
constexpr int D = 16;
constexpr int R = 32;
constexpr int H = 64;
constexpr int E = 262144;   // 2^18

typedef __attribute__((ext_vector_type(8))) short short8;   // 8 x bf16 (4 VGPRs)
typedef __attribute__((ext_vector_type(4))) short short4v;  // 4 x bf16 (2 VGPRs)
typedef __attribute__((ext_vector_type(4))) float f32x4;    // MFMA accumulator

__device__ __forceinline__ float4 ld4(const float* p) {
    return *reinterpret_cast<const float4*>(p);
}
__device__ __forceinline__ float4 fma4(float a, float4 w, float4 c) {
    return float4{fmaf(a, w.x, c.x), fmaf(a, w.y, c.y),
                  fmaf(a, w.z, c.z), fmaf(a, w.w, c.w)};
}
__device__ __forceinline__ float4 relu4(float4 v) {
    return float4{fmaxf(v.x, 0.f), fmaxf(v.y, 0.f), fmaxf(v.z, 0.f), fmaxf(v.w, 0.f)};
}
__device__ __forceinline__ short bf16s(float f) {
    __hip_bfloat16 h = __float2bfloat16(f);   // RNE
    return __builtin_bit_cast(short, h);
}
__device__ __forceinline__ short8 pack8(float4 a, float4 b) {
    short8 o;
    o[0] = bf16s(a.x); o[1] = bf16s(a.y); o[2] = bf16s(a.z); o[3] = bf16s(a.w);
    o[4] = bf16s(b.x); o[5] = bf16s(b.y); o[6] = bf16s(b.z); o[7] = bf16s(b.w);
    return o;
}
// relu + pack 4 accumulator floats into 4 bf16
__device__ __forceinline__ short4v pack4_relu(f32x4 c) {
    short4v o;
    o[0] = bf16s(fmaxf(c[0], 0.f)); o[1] = bf16s(fmaxf(c[1], 0.f));
    o[2] = bf16s(fmaxf(c[2], 0.f)); o[3] = bf16s(fmaxf(c[3], 0.f));
    return o;
}
// concat two packed short4v into an MFMA A/B fragment (pure register op)
__device__ __forceinline__ short8 cat44(short4v a, short4v b) {
    int2 ia = __builtin_bit_cast(int2, a);
    int2 ib = __builtin_bit_cast(int2, b);
    int4 v{ia.x, ia.y, ib.x, ib.y};
    return __builtin_bit_cast(short8, v);
}
// extract position i (0..31) from 4x int4 of packed bf16 (i must be compile-time)
__device__ __forceinline__ float red_get(const int4* uu, int i) {
    const int wsel = i >> 1;
    const int4 v = uu[wsel >> 2];
    const int word = (wsel & 3) == 0 ? v.x : (wsel & 3) == 1 ? v.y
                   : (wsel & 3) == 2 ? v.z : v.w;
    return (i & 1) ? __builtin_bit_cast(float, word & 0xffff0000)
                   : __builtin_bit_cast(float, (unsigned)word << 16);
}

constexpr int RED_S = 264;   // red stride in shorts; %8==0 keeps b128 reads 16B-aligned

// hidden-permutation for layer-2/4 row packing (R5-verified): the C/D accumulator
// of layer 1/3 (lane q*16+l15, tile mt, reg rg = hidden mt*16+q*4+rg) is consumed
// DIRECTLY as the next layer's A/B fragment (k = q*8+j) iff row k sources hidden
//   rho(k) = 32*(k>>5) + ((k>>2)&1)*16 + ((k>>3)&3)*4 + (k&3)
// Then h0 = concat(tile0,tile1), h1 = concat(tile2,tile3): NO LDS transpose.

__device__ __forceinline__ void prepack_w12(
    int t, const float* __restrict__ W1, const float* __restrict__ W2,
    short* __restrict__ w1p, short* __restrict__ w2p)
{
    // A/B-frag mapping (mfma_f32_16x16x32_bf16, verified m89):
    //   m|n = lane&15, k = (lane>>4)*8 + j  (identical for A and B)
    for (int i = t; i < 4 * 64 * 8; i += 256) {
        int j = i & 7, lane = (i >> 3) & 63, ct = i >> 9;
        int k = (lane >> 4) * 8 + j, n = ct * 16 + (lane & 15);
        w1p[i] = bf16s(W1[k * H + n]);
    }
    for (int i = t; i < 4 * 64 * 8; i += 256) {
        int j = i & 7, lane = (i >> 3) & 63, idx = i >> 9;
        int ct = idx >> 1, kc = idx & 1;
        // rho-remapped row: was kc*32 + (lane>>4)*8 + j
        int k = kc * 32 + (j >> 2) * 16 + ((lane >> 4) & 3) * 4 + (j & 3);
        int f = ct * 16 + (lane & 15);
        w2p[i] = bf16s(W2[k * R + f]);
    }
}
__device__ __forceinline__ void prepack_w34(
    int t, const float* __restrict__ W3, const float* __restrict__ W4,
    short* __restrict__ w3p, short* __restrict__ w4p)
{
    for (int i = t; i < 8 * 64 * 8; i += 256) {
        int j = i & 7, lane = (i >> 3) & 63, idx = i >> 9;
        int ct = idx >> 1, kc = idx & 1;
        int k = kc * 32 + (lane >> 4) * 8 + j, n = ct * 16 + (lane & 15);
        w3p[i] = (k < D + R) ? bf16s(W3[k * H + n]) : (short)0;
    }
    for (int i = t; i < 2 * 64 * 8; i += 256) {
        int j = i & 7, lane = (i >> 3) & 63, kc = i >> 9;
        // rho-remapped row: was kc*32 + (lane>>4)*8 + j
        int k = kc * 32 + (j >> 2) * 16 + ((lane >> 4) & 3) * 4 + (j & 3);
        int d = lane & 15;
        w4p[i] = bf16s(W4[k * D + d]);
    }
}

// ---------------------------------------------------------------------------
// Dispatch 2: histogram (blocks 0..1023), weight prepack (block 1024),
//             rel zero (blocks 1025..1152).  (R0/R6-proven structure)
// ---------------------------------------------------------------------------
__global__ __launch_bounds__(256) void hist_prepack_kernel(
    const int* __restrict__ receivers, int* __restrict__ cnt,
    const float* __restrict__ W1, const float* __restrict__ W2,
    const float* __restrict__ W3, const float* __restrict__ W4,
    short* __restrict__ w1p, short* __restrict__ w2p,
    short* __restrict__ w3p, short* __restrict__ w4p,
    float4* __restrict__ relz)
{
    if (blockIdx.x < 1024) {
        int e = blockIdx.x * 256 + threadIdx.x;
        atomicAdd(cnt + receivers[e], 1);
        return;
    }
    if (blockIdx.x >= 1025) {
        const int base = (blockIdx.x - 1025) * 256 + threadIdx.x;
        #pragma unroll
        for (int i = 0; i < 8; ++i)
            relz[base + i * 32768] = float4{0.f, 0.f, 0.f, 0.f};
        return;
    }
    prepack_w12(threadIdx.x, W1, W2, w1p, w2p);
    prepack_w34(threadIdx.x, W3, W4, w3p, w4p);
}

// ---------------------------------------------------------------------------
// Dispatch 3 (scan+scatter fused, NO inter-block sync): the exclusive scan is
// a pure function of cnt, so every block recomputes it redundantly (32 KB L2-
// hot reads + shfl scan, ~2 µs) instead of a separate 1-block scan dispatch.
// Scan stored TRANSPOSED in LDS (write banks = tid%32, 2-way = free):
//   node n -> scan_t[(n&31)*256 + (n>>5)]
// Scatter: p = scan_t[r] + atomicAdd(poscnt + r, 1)  (poscnt memset-zeroed).
// Saves one dispatch boundary vs R6; within-receiver order remains
// nondeterministic exactly as before (sum is order-independent at fp32 level
// only via atomics — matches prior rounds' accepted tolerance).
// ---------------------------------------------------------------------------
__global__ __launch_bounds__(256, 4) void scanscatter_kernel(
    const int* __restrict__ senders, const int* __restrict__ receivers,
    const int* __restrict__ cnt, int* __restrict__ poscnt,
    int2* __restrict__ sr)
{
    __shared__ int scan_t[N];      // 32 KB, transposed layout
    __shared__ int wtot[4];

    const int tid = threadIdx.x;
    const int e = blockIdx.x * 256 + tid;
    const int r = receivers[e];
    const int s = senders[e];

    // block-redundant exclusive scan of cnt[8192], 32 counts/thread
    int4 c4[8];
    const int4* cp = reinterpret_cast<const int4*>(cnt) + tid * 8;
    #pragma unroll
    for (int i = 0; i < 8; ++i) c4[i] = cp[i];
    int c[32];
    #pragma unroll
    for (int i = 0; i < 8; ++i) {
        c[4 * i + 0] = c4[i].x; c[4 * i + 1] = c4[i].y;
        c[4 * i + 2] = c4[i].z; c[4 * i + 3] = c4[i].w;
    }
    int s0 = 0;
    #pragma unroll
    for (int i = 0; i < 32; ++i) s0 += c[i];
    const int lane = tid & 63, wv = tid >> 6;
    int incl = s0;
    #pragma unroll
    for (int d = 1; d < 64; d <<= 1) {
        int v = __shfl_up(incl, d, 64);
        if (lane >= d) incl += v;
    }
    if (lane == 63) wtot[wv] = incl;
    __syncthreads();
    int base = incl - s0;
    #pragma unroll
    for (int i = 0; i < 4; ++i) base += (i < wv) ? wtot[i] : 0;
    // transposed store: node n = tid*32 + i  ->  scan_t[i*256 + tid]
    #pragma unroll
    for (int i = 0; i < 32; ++i) {
        scan_t[i * 256 + tid] = base;
        base += c[i];
    }
    __syncthreads();

    const int p = scan_t[(r & 31) * 256 + (r >> 5)] + atomicAdd(poscnt + r, 1);
    sr[p] = int2{s, r};
}

// ---------------------------------------------------------------------------
// Dispatch 4: MFMA edge MLP + two-stage segmented reduction (4096 blocks).
// rho-remap: no LDS transpose (R5-verified). Two-stage reduction (R4-verified):
// only first/last receivers of a window can straddle blocks -> atomicAdd;
// interior receivers -> plain stores into pre-zeroed rel.
// ---------------------------------------------------------------------------
__global__ __launch_bounds__(256, 4) void edge_mfma_kernel(
    const float* __restrict__ particles,
    const int2*  __restrict__ sr,
    const short* __restrict__ w1p, const float* __restrict__ b1,
    const short* __restrict__ w2p, const float* __restrict__ b2,
    float* __restrict__ rel)
{
    __shared__ short red[R * RED_S];          // [f][pos] bf16, stride 264 (16.9 KB)
    __shared__ int   rs[256];
    __shared__ float pre[8][33];              // first-segment sum per (group,feat)
    __shared__ float suf[8][33];              // last-segment sum per (group,feat)
    __shared__ int   kcnt[8];                 // segments per group

    const int tid  = threadIdx.x;
    const int lane = tid & 63;
    const int w    = tid >> 6;
    const int b    = blockIdx.x >> 10;        // 1024 blocks per batch
    const int p0   = (blockIdx.x & 1023) * 256;
    const int l15  = lane & 15;
    const int q    = lane >> 4;

    const int2 srv = sr[p0 + tid];
    rs[tid] = srv.y;

    // hoisted gather: distribute rows via shfl, issue all 8 dwordx4 loads up front
    float4 a0[4], a1[4];
    #pragma unroll
    for (int t = 0; t < 4; ++t) {
        int srow = __shfl(srv.x, t * 16 + l15);
        int rrow = __shfl(srv.y, t * 16 + l15);
        int row = (q < 2) ? srow : rrow;
        const float* src = particles + ((size_t)b * N + row) * D + (q & 1) * 8;
        a0[t] = ld4(src);
        a1[t] = ld4(src + 4);
    }

    // weight fragments (L2-hot, coalesced)
    short8 w1f[4], w2f[4];
    #pragma unroll
    for (int mt = 0; mt < 4; ++mt)
        w1f[mt] = *reinterpret_cast<const short8*>(w1p + (mt * 64 + lane) * 8);
    #pragma unroll
    for (int i = 0; i < 4; ++i)
        w2f[i] = *reinterpret_cast<const short8*>(w2p + (i * 64 + lane) * 8);

    f32x4 bias1[4];
    #pragma unroll
    for (int mt = 0; mt < 4; ++mt) {
        float4 t4 = ld4(b1 + mt * 16 + q * 4);
        bias1[mt] = f32x4{t4.x, t4.y, t4.z, t4.w};
    }
    const float bias2a = b2[l15];
    const float bias2b = b2[16 + l15];

    short8 af[4];
    #pragma unroll
    for (int t = 0; t < 4; ++t) af[t] = pack8(a0[t], a1[t]);

    #pragma unroll
    for (int t = 0; t < 4; ++t) {
        // layer1: 4 hidden m-tiles, K=32 -> packed bf16 kept in registers
        f32x4 c0 = __builtin_amdgcn_mfma_f32_16x16x32_bf16(w1f[0], af[t], bias1[0], 0, 0, 0);
        f32x4 c1 = __builtin_amdgcn_mfma_f32_16x16x32_bf16(w1f[1], af[t], bias1[1], 0, 0, 0);
        f32x4 c2 = __builtin_amdgcn_mfma_f32_16x16x32_bf16(w1f[2], af[t], bias1[2], 0, 0, 0);
        f32x4 c3 = __builtin_amdgcn_mfma_f32_16x16x32_bf16(w1f[3], af[t], bias1[3], 0, 0, 0);
        short8 h0 = cat44(pack4_relu(c0), pack4_relu(c1));   // k = 0..31 (rho rows)
        short8 h1 = cat44(pack4_relu(c2), pack4_relu(c3));   // k = 32..63

        // layer2: D2[edge][f], 2 f-tiles, K=64
        f32x4 r0 = {bias2a, bias2a, bias2a, bias2a};
        f32x4 r1 = {bias2b, bias2b, bias2b, bias2b};
        r0 = __builtin_amdgcn_mfma_f32_16x16x32_bf16(h0, w2f[0], r0, 0, 0, 0);
        r0 = __builtin_amdgcn_mfma_f32_16x16x32_bf16(h1, w2f[1], r0, 0, 0, 0);
        r1 = __builtin_amdgcn_mfma_f32_16x16x32_bf16(h0, w2f[2], r1, 0, 0, 0);
        r1 = __builtin_amdgcn_mfma_f32_16x16x32_bf16(h1, w2f[3], r1, 0, 0, 0);

        const int pb2 = w * 64 + t * 16 + q * 4;
        *reinterpret_cast<short4v*>(red + l15 * RED_S + pb2)        = pack4_relu(r0);
        *reinterpret_cast<short4v*>(red + (16 + l15) * RED_S + pb2) = pack4_relu(r1);
    }
    __syncthreads();

    // ---- stage 1: per-(group,feature) segmented partial sums ----
    const int g2 = tid >> 5;
    const int f  = tid & 31;
    const int gb = g2 * 32;
    float* relb = rel + (size_t)b * N * R;

    unsigned bmask = 0;
    int first;
    {
        int4 r4[8];
        #pragma unroll
        for (int i = 0; i < 8; ++i)
            r4[i] = *reinterpret_cast<const int4*>(rs + gb + 4 * i);
        first = r4[0].x;
        int prev = first;
        #pragma unroll
        for (int i = 1; i < 32; ++i) {
            const int4 v4 = r4[i >> 2];
            const int rr = (i & 3) == 0 ? v4.x : (i & 3) == 1 ? v4.y
                         : (i & 3) == 2 ? v4.z : v4.w;
            if (rr != prev) bmask |= (1u << i);
            prev = rr;
        }
    }
    if (f == 0) kcnt[g2] = __popc(bmask) + 1;

    int4 uu[4];
    #pragma unroll
    for (int i = 0; i < 4; ++i)
        uu[i] = *reinterpret_cast<const int4*>(red + f * RED_S + gb + 8 * i);

    {
        float acc = 0.f;
        int cur = first;
        int seg = 0;
        #pragma unroll
        for (int i = 0; i < 32; ++i) {
            if (bmask & (1u << i)) {
                if (seg == 0) pre[g2][f] = acc;
                else relb[(size_t)cur * R + f] = acc;   // interior complete receiver
                ++seg;
                acc = 0.f;
                cur = rs[gb + i];
            }
            acc += red_get(uu, i);
        }
        suf[g2][f] = acc;   // last segment (k==1: whole group; pre unwritten)
    }
    __syncthreads();

    // ---- stage 2: merge chains across groups (one thread per feature) ----
    if (tid < 32) {
        int   cur2 = rs[0];
        float a2   = 0.f;
        int   nfl  = 0;
        #pragma unroll
        for (int g = 0; g < 8; ++g) {
            const int   rf   = rs[g * 32];
            const int   rl   = rs[g * 32 + 31];
            const int   kk   = kcnt[g];
            const float sufv = suf[g][tid];
            if (kk == 1) {
                if (rf == cur2) a2 += sufv;
                else {
                    if (nfl == 0) atomicAdd(relb + (size_t)cur2 * R + tid, a2);
                    else          relb[(size_t)cur2 * R + tid] = a2;
                    ++nfl;
                    cur2 = rf; a2 = sufv;
                }
            } else {
                const float prev = pre[g][tid];
                if (rf == cur2) {
                    a2 += prev;
                    if (nfl == 0) atomicAdd(relb + (size_t)cur2 * R + tid, a2);
                    else          relb[(size_t)cur2 * R + tid] = a2;
                    ++nfl;
                } else {
                    if (nfl == 0) atomicAdd(relb + (size_t)cur2 * R + tid, a2);
                    else          relb[(size_t)cur2 * R + tid] = a2;
                    ++nfl;
                    relb[(size_t)rf * R + tid] = prev;   // complete receiver
                    ++nfl;
                }
                cur2 = rl; a2 = sufv;
            }
        }
        atomicAdd(relb + (size_t)cur2 * R + tid, a2);   // may span into next window
    }
}

// ---------------------------------------------------------------------------
// Dispatch 5: MFMA node MLP, one 16-node tile per wave. Zero LDS (rho-remap).
// ---------------------------------------------------------------------------
__global__ __launch_bounds__(256, 4) void node_mfma_kernel(
    const float* __restrict__ particles,
    const float* __restrict__ rel,
    const short* __restrict__ w3p, const float* __restrict__ b3,
    const short* __restrict__ w4p, const float* __restrict__ b4,
    float* __restrict__ out)
{
    const int tid  = threadIdx.x;
    const int lane = tid & 63;
    const int w    = tid >> 6;
    const int tile = blockIdx.x * 4 + w;        // [0, B*N/16)
    const int b    = tile >> 9;                 // 512 tiles per batch
    const int l15  = lane & 15;
    const int q    = lane >> 4;
    const int node = (tile & 511) * 16 + l15;

    const float* prow = particles + ((size_t)b * N + node) * D;
    const float* rrow = rel + ((size_t)b * N + node) * R;

    const float* src0 = (q < 2) ? (prow + (q & 1) * 8) : (rrow + (q & 1) * 8);
    float4 c0a = ld4(src0), c0b = ld4(src0 + 4);
    float4 c1a = {0.f, 0.f, 0.f, 0.f}, c1b = {0.f, 0.f, 0.f, 0.f};
    if (q < 2) { c1a = ld4(rrow + 16 + q * 8); c1b = ld4(rrow + 20 + q * 8); }

    short8 w3f[8], w4f[2];
    #pragma unroll
    for (int i = 0; i < 8; ++i)
        w3f[i] = *reinterpret_cast<const short8*>(w3p + (i * 64 + lane) * 8);
    #pragma unroll
    for (int i = 0; i < 2; ++i)
        w4f[i] = *reinterpret_cast<const short8*>(w4p + (i * 64 + lane) * 8);

    f32x4 bias3[4];
    #pragma unroll
    for (int mt = 0; mt < 4; ++mt) {
        float4 t4 = ld4(b3 + mt * 16 + q * 4);
        bias3[mt] = f32x4{t4.x, t4.y, t4.z, t4.w};
    }
    f32x4 bias4;
    { float4 t4 = ld4(b4 + q * 4); bias4 = f32x4{t4.x, t4.y, t4.z, t4.w}; }

    short8 a0 = pack8(c0a, c0b);
    short8 a1 = pack8(c1a, c1b);

    // layer3: 4 hidden m-tiles, K=48 (padded 64) -> packed in registers
    f32x4 c0 = bias3[0], c1 = bias3[1], c2 = bias3[2], c3 = bias3[3];
    c0 = __builtin_amdgcn_mfma_f32_16x16x32_bf16(w3f[0], a0, c0, 0, 0, 0);
    c0 = __builtin_amdgcn_mfma_f32_16x16x32_bf16(w3f[1], a1, c0, 0, 0, 0);
    c1 = __builtin_amdgcn_mfma_f32_16x16x32_bf16(w3f[2], a0, c1, 0, 0, 0);
    c1 = __builtin_amdgcn_mfma_f32_16x16x32_bf16(w3f[3], a1, c1, 0, 0, 0);
    c2 = __builtin_amdgcn_mfma_f32_16x16x32_bf16(w3f[4], a0, c2, 0, 0, 0);
    c2 = __builtin_amdgcn_mfma_f32_16x16x32_bf16(w3f[5], a1, c2, 0, 0, 0);
    c3 = __builtin_amdgcn_mfma_f32_16x16x32_bf16(w3f[6], a0, c3, 0, 0, 0);
    c3 = __builtin_amdgcn_mfma_f32_16x16x32_bf16(w3f[7], a1, c3, 0, 0, 0);
    short8 h0 = cat44(pack4_relu(c0), pack4_relu(c1));   // k = 0..31 (rho rows)
    short8 h1 = cat44(pack4_relu(c2), pack4_relu(c3));   // k = 32..63

    f32x4 r = bias4;
    r = __builtin_amdgcn_mfma_f32_16x16x32_bf16(w4f[0], h0, r, 0, 0, 0);
    r = __builtin_amdgcn_mfma_f32_16x16x32_bf16(w4f[1], h1, r, 0, 0, 0);

    float4 pv = ld4(prow + q * 4);
    float4* po = reinterpret_cast<float4*>(out + ((size_t)b * N + node) * D + q * 4);
    *po = float4{pv.x + r[0], pv.y + r[1], pv.z + r[2], pv.w + r[3]};
}

// ---------- fallback path (fp32, correctness backstop) ----------

__global__ __launch_bounds__(256, 2) void edge_atomic_kernel(
    const float* __restrict__ particles,
    const int*   __restrict__ senders,
    const int*   __restrict__ receivers,
    const float* __restrict__ W1, const float* __restrict__ b1,
    const float* __restrict__ W2, const float* __restrict__ b2,
    float* __restrict__ rel)
{
    const int idx = blockIdx.x * 256 + threadIdx.x;
    const int b = idx >> 18;
    const int e = idx & (E - 1);
    const int s = senders[e];
    const int r = receivers[e];

    float4 ein4[8];
    {
        const float4* ps = reinterpret_cast<const float4*>(particles + ((size_t)b * N + s) * D);
        const float4* pr = reinterpret_cast<const float4*>(particles + ((size_t)b * N + r) * D);
        #pragma unroll
        for (int qq = 0; qq < 4; ++qq) ein4[qq] = ps[qq];
        #pragma unroll
        for (int qq = 0; qq < 4; ++qq) ein4[4 + qq] = pr[qq];
    }
    float4 rf4[8];
    #pragma unroll
    for (int qq = 0; qq < 8; ++qq) rf4[qq] = ld4(b2 + 4 * qq);

    for (int j4 = 0; j4 < H / 4; ++j4) {
        float4 h = ld4(b1 + 4 * j4);
        const float* w1c = W1 + 4 * j4;
        #pragma unroll
        for (int kv = 0; kv < 8; ++kv) {
            const float4 ev = ein4[kv];
            h = fma4(ev.x, ld4(w1c + (4 * kv + 0) * H), h);
            h = fma4(ev.y, ld4(w1c + (4 * kv + 1) * H), h);
            h = fma4(ev.z, ld4(w1c + (4 * kv + 2) * H), h);
            h = fma4(ev.w, ld4(w1c + (4 * kv + 3) * H), h);
        }
        h = relu4(h);
        const float* w2r = W2 + (4 * j4) * R;
        #pragma unroll
        for (int qq = 0; qq < 4; ++qq) {
            const float hq = (qq == 0) ? h.x : (qq == 1) ? h.y : (qq == 2) ? h.z : h.w;
            #pragma unroll
            for (int r4 = 0; r4 < 8; ++r4)
                rf4[r4] = fma4(hq, ld4(w2r + qq * R + 4 * r4), rf4[r4]);
        }
    }
    float* dst = rel + ((size_t)b * N + r) * R;
    #pragma unroll
    for (int r4 = 0; r4 < 8; ++r4) {
        float4 v = relu4(rf4[r4]);
        atomicAdd(dst + 4 * r4 + 0, v.x);
        atomicAdd(dst + 4 * r4 + 1, v.y);
        atomicAdd(dst + 4 * r4 + 2, v.z);
        atomicAdd(dst + 4 * r4 + 3, v.w);
    }
}

__global__ __launch_bounds__(256, 2) void node_valu_kernel(
    const float* __restrict__ particles,
    const float* __restrict__ rel,
    const float* __restrict__ W3, const float* __restrict__ b3,
    const float* __restrict__ W4, const float* __restrict__ b4,
    float* __restrict__ out)
{
    const int idx = blockIdx.x * 256 + threadIdx.x;
    float4 in4[12];
    {
        const float4* pp = reinterpret_cast<const float4*>(particles + (size_t)idx * D);
        #pragma unroll
        for (int qq = 0; qq < 4; ++qq) in4[qq] = pp[qq];
        const float4* pr = reinterpret_cast<const float4*>(rel + (size_t)idx * R);
        #pragma unroll
        for (int qq = 0; qq < 8; ++qq) in4[4 + qq] = pr[qq];
    }
    float4 dl4[4];
    #pragma unroll
    for (int qq = 0; qq < 4; ++qq) dl4[qq] = ld4(b4 + 4 * qq);

    for (int j4 = 0; j4 < H / 4; ++j4) {
        float4 h = ld4(b3 + 4 * j4);
        const float* w3c = W3 + 4 * j4;
        #pragma unroll
        for (int kv = 0; kv < 12; ++kv) {
            const float4 ev = in4[kv];
            h = fma4(ev.x, ld4(w3c + (4 * kv + 0) * H), h);
            h = fma4(ev.y, ld4(w3c + (4 * kv + 1) * H), h);
            h = fma4(ev.z, ld4(w3c + (4 * kv + 2) * H), h);
            h = fma4(ev.w, ld4(w3c + (4 * kv + 3) * H), h);
        }
        h = relu4(h);
        const float* w4r = W4 + (4 * j4) * D;
        #pragma unroll
        for (int qq = 0; qq < 4; ++qq) {
            const float hq = (qq == 0) ? h.x : (qq == 1) ? h.y : (qq == 2) ? h.z : h.w;
            #pragma unroll
            for (int d4 = 0; d4 < 4; ++d4)
                dl4[d4] = fma4(hq, ld4(w4r + qq * D + 4 * d4), dl4[d4]);
        }
    }
    float4* po = reinterpret_cast<float4*>(out + (size_t)idx * D);
    #pragma unroll
    for (int qq = 0; qq < 4; ++qq) {
        float4 v = dl4[qq];
        float4 pv = in4[qq];
        po[qq] = float4{pv.x + v.x, pv.y + v.y, pv.z + v.z, pv.w + v.w};
    }
}

}  // namespace

extern "C" void kernel_launch(void* const* d_in, const int* in_sizes, int n_in,
                              void* d_out, int out_size, void* d_ws, size_t ws_size,
                              hipStream_t stream) {
    const float* particles = (const float*)d_in[0];
    const int*   senders   = (const int*)d_in[1];
    const int*   receivers = (const int*)d_in[2];
    const float* W1 = (const float*)d_in[3];
    const float* b1 = (const float*)d_in[4];
    const float* W2 = (const float*)d_in[5];
    const float* b2 = (const float*)d_in[6];
    const float* W3 = (const float*)d_in[7];
    const float* b3 = (const float*)d_in[8];
    const float* W4 = (const float*)d_in[9];
    const float* b4 = (const float*)d_in[10];
    float* out = (float*)d_out;

    // workspace layout (256-B aligned slices); cnt and poscnt contiguous so a
    // single memset covers both (N*4 = 32768 is already 256-aligned).
    char* ws = (char*)d_ws;
    size_t off = 0;
    auto take = [&](size_t bytes) -> char* {
        char* p = ws + off;
        off = (off + bytes + 255) & ~(size_t)255;
        return p;
    };
    int*   cnt     = (int*)  take((size_t)N * 4);
    int*   poscnt  = (int*)  take((size_t)N * 4);
    int2*  sr      = (int2*) take((size_t)E * 8);
    float* rel     = (float*)take((size_t)B * N * R * 4);
    short* w1p     = (short*)take((size_t)4 * 64 * 8 * 2);
    short* w2p     = (short*)take((size_t)4 * 64 * 8 * 2);
    short* w3p     = (short*)take((size_t)8 * 64 * 8 * 2);
    short* w4p     = (short*)take((size_t)2 * 64 * 8 * 2);
    const bool fast = (off <= ws_size);

    if (fast) {
        hipMemsetAsync(cnt, 0, (size_t)2 * N * 4, stream);   // cnt + poscnt
        hist_prepack_kernel<<<1153, 256, 0, stream>>>(
            receivers, cnt, W1, W2, W3, W4, w1p, w2p, w3p, w4p, (float4*)rel);
        scanscatter_kernel<<<E / 256, 256, 0, stream>>>(
            senders, receivers, cnt, poscnt, sr);
        edge_mfma_kernel<<<(B * E) / 256, 256, 0, stream>>>(
            particles, sr, w1p, b1, w2p, b2, rel);
        node_mfma_kernel<<<(B * N / 16) / 4, 256, 0, stream>>>(
            particles, rel, w3p, b3, w4p, b4, out);
    } else {
        float* rel0 = (float*)d_ws;
        hipMemsetAsync(rel0, 0, (size_t)B * N * R * 4, stream);
        edge_atomic_kernel<<<(B * E) / 256, 256, 0, stream>>>(
            particles, senders, receivers, W1, b1, W2, b2, rel0);
        node_valu_kernel<<<(B * N) / 256, 256, 0, stream>>>(
            particles, rel0, W3, b3, W4, b4, out);
    }
}